// Round 25
// baseline (65.590 us; speedup 1.0000x reference)
//
#include <hip/hip_runtime.h>
#include <hip/hip_bf16.h>

// Interpolator == attention: out = softmax_c(z_t^T (W+W^T) z_c - q_cc[c]) @ y_context
// Msym = log2e*(W+W^T) f32; Q = z_target @ Msym (hi/lo bf16); K = z_context (hi/lo bf16)
// bias[c] = -0.5 * z_c^T Msym z_c (f32); V^T bf16 [32][8192]. No online max.
//
// R25 = R24 with ONE parameter change in attn: supertile 128 -> 64 contexts.
// LDS 75776 -> 38912 B => 4 blocks/CU co-resident; other blocks' compute hides
// each block's stage+barrier (R24: 2 blocks/CU, ~10us exposed stage latency).
// Inner dataflow (per-cb fused body, p_lds entry algebra, MFMA patterns,
// epilogue) is R24-IDENTICAL -- only trip counts halve (cb 4, ks 2, st 16) and
// VL rows are 64 bf16 (8 chunks, phys = chunk ^ (row&7), 2-way conflict = free).
// VGPR need 52 < 64 cap -> R17's spill trap impossible at any occupancy target.

typedef float f32x4 __attribute__((ext_vector_type(4)));
typedef __bf16 bf16x8 __attribute__((ext_vector_type(8)));

#define LOG2E 1.4426950408889634f

static __device__ __forceinline__ unsigned short f2bf(float x) {
  unsigned u = __float_as_uint(x);
  u += 0x7fffu + ((u >> 16) & 1u);   // RNE
  return (unsigned short)(u >> 16);
}
static __device__ __forceinline__ float bf2f(unsigned short h) {
  return __uint_as_float(((unsigned)h) << 16);
}
static __device__ __forceinline__ bf16x8 ldg8(const unsigned short* p) {
  uint4 u = *reinterpret_cast<const uint4*>(p);
  return __builtin_bit_cast(bf16x8, u);
}
static __device__ __forceinline__ unsigned cvt_pk_bf16(float lo, float hi) {
  unsigned r;
  asm("v_cvt_pk_bf16_f32 %0, %1, %2" : "=v"(r) : "v"(lo), "v"(hi));
  return r;
}
// direct global->LDS DMA, 16B/lane; LDS dest = wave-uniform base + lane*16
static __device__ __forceinline__ void gl2lds(const unsigned short* g, unsigned short* l) {
  __builtin_amdgcn_global_load_lds(
      (const __attribute__((address_space(1))) unsigned int*)g,
      (__attribute__((address_space(3))) unsigned int*)l, 16, 0, 0);
}

// grid 1072: b<16 -> Msym (4096 elems); b>=16 -> zero out (262144) + denA (8192).
// Coverage: 1056 blocks x 256 = 270336 = 262144 + 8192, EXACT. (R19 byte-exact)
__global__ void msym_kernel(const float* __restrict__ W, float* __restrict__ Msym,
                            float* __restrict__ out, float* __restrict__ denA) {
  int b = blockIdx.x, tid = threadIdx.x;
  if (b < 16) {
    int idx = b * 256 + tid;
    int k = idx >> 6, d = idx & 63;
    Msym[idx] = LOG2E * (W[k * 64 + d] + W[d * 64 + k]);
  } else {
    int idx = (b - 16) * 256 + tid;           // [0, 270336)
    if (idx < 262144) out[idx] = 0.f;
    else denA[idx - 262144] = 0.f;
  }
}

// grid 3104: [0,512) Q (16 t/block) | [512,2560) K | [2560,3072) bias (16 c/block)
//          | [3072,3104) V-transpose   (R24 byte-exact)
__global__ void prep_kernel(const float* __restrict__ zc, const float* __restrict__ yc,
                            const float* __restrict__ zt, const float* __restrict__ Msym,
                            unsigned short* __restrict__ Qh, unsigned short* __restrict__ Ql,
                            unsigned short* __restrict__ Kh, unsigned short* __restrict__ Kl,
                            unsigned short* __restrict__ Vt, float* __restrict__ bias)
{
  int b = blockIdx.x, tid = threadIdx.x;
  if (b < 512) {                        // Q = z_t @ Msym, 16 targets/block (4/wave)
    int d = tid & 63, grp = tid >> 6;
    int t0 = b * 16 + grp * 4;          // this wave's 4 targets
    const float* z0 = zt + t0 * 64;
    float q0 = 0.f, q1 = 0.f, q2 = 0.f, q3 = 0.f;
    #pragma unroll 8
    for (int k = 0; k < 64; ++k) {
      float m = Msym[k * 64 + d];       // one coalesced load, reused x4
      q0 = fmaf(z0[k], m, q0);
      q1 = fmaf(z0[64 + k], m, q1);
      q2 = fmaf(z0[128 + k], m, q2);
      q3 = fmaf(z0[192 + k], m, q3);
    }
    float qv[4] = {q0, q1, q2, q3};
    #pragma unroll
    for (int i = 0; i < 4; ++i) {
      int idx = (t0 + i) * 64 + d;
      unsigned short h = f2bf(qv[i]);
      Qh[idx] = h;
      Ql[idx] = f2bf(qv[i] - bf2f(h));
    }
  } else if (b < 2560) {                // K hi/lo split
    int idx = (b - 512) * 256 + tid;
    float v = zc[idx];
    unsigned short h = f2bf(v);
    Kh[idx] = h;
    Kl[idx] = f2bf(v - bf2f(h));
  } else if (b < 3072) {                // bias, 16 contexts/block (4/wave)
    int j = tid & 63, grp = tid >> 6;
    int c0 = (b - 2560) * 16 + grp * 4;
    const float* z0 = zc + c0 * 64;
    float s0 = 0.f, s1 = 0.f, s2 = 0.f, s3 = 0.f;
    #pragma unroll 8
    for (int i = 0; i < 64; ++i) {
      float m = Msym[i * 64 + j];       // one coalesced load, reused x4
      s0 = fmaf(z0[i], m, s0);
      s1 = fmaf(z0[64 + i], m, s1);
      s2 = fmaf(z0[128 + i], m, s2);
      s3 = fmaf(z0[192 + i], m, s3);
    }
    float part[4];
    part[0] = s0 * z0[j];
    part[1] = s1 * z0[64 + j];
    part[2] = s2 * z0[128 + j];
    part[3] = s3 * z0[192 + j];
    #pragma unroll
    for (int i = 0; i < 4; ++i) {
      #pragma unroll
      for (int off = 32; off >= 1; off >>= 1) part[i] += __shfl_xor(part[i], off, 64);
    }
    if (j < 4) bias[c0 + j] = -0.5f * part[j];
  } else {                              // V transpose via LDS (alignment-safe)
    __shared__ float vt[256][33];
    int cbase = (b - 3072) * 256;       // 256 contexts per block
    #pragma unroll
    for (int k = 0; k < 32; ++k) {
      int e = k * 256 + tid;            // e = c_rel*32 + dy, coalesced read
      vt[e >> 5][e & 31] = yc[cbase * 32 + e];
    }
    __syncthreads();
    #pragma unroll
    for (int k = 0; k < 32; ++k)        // k = dy; consecutive tid -> consecutive c
      Vt[k * 8192 + cbase + tid] = f2bf(vt[tid][k]);
  }
}

// ---------------- attention kernel (R24 body, 64-context supertile) ----------
// KhL/KlL: 64 rows x 128B, 8 chunks of 16B, physical chunk p holds logical
// p ^ (row&7) (SAME formula as R24). VL: 32 rows x 128B (64 bf16), 8 chunks,
// physical p holds logical p ^ (row&7). Staging pre-swizzles the GLOBAL source.

#define STAGE(C0) { \
  const int C0_ = (C0); \
  {                                             /* 8 K instr-groups, 1/wave */ \
    int row = wid * 8 + (lane >> 3); \
    int lchunk = (lane & 7) ^ (lane >> 3); \
    gl2lds(Kh + (C0_ + row) * 64 + lchunk * 8, &KhL[wid * 512]); \
    gl2lds(Kl + (C0_ + row) * 64 + lchunk * 8, &KlL[wid * 512]); \
  } \
  if (wid < 4) {                                /* 4 V instr-groups */ \
    int row = wid * 8 + (lane >> 3);            /* rows = dy 0..31 */ \
    int lchunk = (lane & 7) ^ (row & 7); \
    gl2lds(Vt + row * 8192 + C0_ + lchunk * 8, &VL[wid * 512]); \
  } }

__global__ __launch_bounds__(512, 4) void attn_kernel(
    const unsigned short* __restrict__ Qh, const unsigned short* __restrict__ Ql,
    const unsigned short* __restrict__ Kh, const unsigned short* __restrict__ Kl,
    const unsigned short* __restrict__ Vt, const float* __restrict__ bias,
    float* __restrict__ outAcc, float* __restrict__ denA)
{
  __shared__ unsigned short KhL[64 * 64];       // 8 KB
  __shared__ unsigned short KlL[64 * 64];       // 8 KB
  __shared__ unsigned short VL[32 * 64];        // 4 KB
  __shared__ __align__(16) uint2 p_lds[8][16][18];  // 18 KB; total 38912 B

  const int tid = threadIdx.x;
  const int wid = tid >> 6, lane = tid & 63;
  const int lr = lane & 15, g = lane >> 4;
  const int tt = blockIdx.x >> 3, cq = blockIdx.x & 7;
  const int tbase = tt * 128 + wid * 16;        // this wave's 16 targets
  const int cqbase = cq * 1024;                 // this block's context eighth

  // Q fragments (B-operand): lane holds Q[tbase + lr][f*32 + 8g .. +7]
  bf16x8 qh[2], ql[2];
  #pragma unroll
  for (int f = 0; f < 2; ++f) {
    int off = (tbase + lr) * 64 + f * 32 + 8 * g;
    qh[f] = ldg8(Qh + off);
    ql[f] = ldg8(Ql + off);
  }

  uint4 ones_bits = make_uint4(0x3F803F80u, 0x3F803F80u, 0x3F803F80u, 0x3F803F80u);
  bf16x8 vones = __builtin_bit_cast(bf16x8, ones_bits);

  f32x4 acc[2];                                 // [dyb]; D: t_rel=4g+r, dy=dyb*16+lr
  f32x4 den;                                    // denominator (all dy cols equal)
  acc[0] = (f32x4)(0.0f);
  acc[1] = (f32x4)(0.0f);
  den = (f32x4)(0.0f);

  for (int st = 0; st < 16; ++st) {
    STAGE(cqbase + st * 64)
    __syncthreads();                            // stage complete (vmcnt drained)

    const int cbias = cqbase + st * 64;

    // --- per-cb fused: QK^T -> +bias -> exp2 -> pack -> p_lds write (R24 body) ---
    #pragma unroll
    for (int cb = 0; cb < 4; ++cb) {
      int row = cb * 16 + lr;
      int phys0 = g ^ (row & 7);
      int phys1 = (4 + g) ^ (row & 7);
      int off0 = row * 64 + phys0 * 8;
      int off1 = row * 64 + phys1 * 8;
      bf16x8 kh0 = __builtin_bit_cast(bf16x8, *reinterpret_cast<const uint4*>(&KhL[off0]));
      bf16x8 kl0 = __builtin_bit_cast(bf16x8, *reinterpret_cast<const uint4*>(&KlL[off0]));
      bf16x8 kh1 = __builtin_bit_cast(bf16x8, *reinterpret_cast<const uint4*>(&KhL[off1]));
      bf16x8 kl1 = __builtin_bit_cast(bf16x8, *reinterpret_cast<const uint4*>(&KlL[off1]));
      f32x4 sv = (f32x4)(0.0f);
      sv = __builtin_amdgcn_mfma_f32_16x16x32_bf16(kh0, qh[0], sv, 0, 0, 0);
      sv = __builtin_amdgcn_mfma_f32_16x16x32_bf16(kl0, qh[0], sv, 0, 0, 0);
      sv = __builtin_amdgcn_mfma_f32_16x16x32_bf16(kh0, ql[0], sv, 0, 0, 0);
      sv = __builtin_amdgcn_mfma_f32_16x16x32_bf16(kh1, qh[1], sv, 0, 0, 0);
      sv = __builtin_amdgcn_mfma_f32_16x16x32_bf16(kl1, qh[1], sv, 0, 0, 0);
      sv = __builtin_amdgcn_mfma_f32_16x16x32_bf16(kh1, ql[1], sv, 0, 0, 0);
      // D-layout: element r <-> context cb*16 + 4g + r, target = tbase + lr
      f32x4 bv = *reinterpret_cast<const f32x4*>(bias + cbias + cb * 16 + 4 * g);
      float p0 = __builtin_amdgcn_exp2f(sv[0] + bv[0]);
      float p1 = __builtin_amdgcn_exp2f(sv[1] + bv[1]);
      float p2 = __builtin_amdgcn_exp2f(sv[2] + bv[2]);
      float p3 = __builtin_amdgcn_exp2f(sv[3] + bv[3]);
      uint2 w2;
      w2.x = cvt_pk_bf16(p0, p1);
      w2.y = cvt_pk_bf16(p2, p3);
      p_lds[wid][lr][cb * 4 + g] = w2;          // entry e holds contexts 4e..4e+3
    }

    // --- PV + ones-denominator over 2 k-slices of 32 contexts (R24 body) ---
    #pragma unroll
    for (int ks = 0; ks < 2; ++ks) {
      uint2 ra = p_lds[wid][lr][ks * 8 + 2 * g];        // c = ks*32+8g .. +3
      uint2 rb = p_lds[wid][lr][ks * 8 + 2 * g + 1];    // c = ks*32+8g+4 .. +7
      bf16x8 pa = __builtin_bit_cast(bf16x8, make_uint4(ra.x, ra.y, rb.x, rb.y));
      #pragma unroll
      for (int dyb = 0; dyb < 2; ++dyb) {
        int row = dyb * 16 + lr;
        int phys = (ks * 4 + g) ^ (row & 7);    // 8-chunk V swizzle
        bf16x8 vf = __builtin_bit_cast(bf16x8, *reinterpret_cast<const uint4*>(&VL[row * 64 + phys * 8]));
        acc[dyb] = __builtin_amdgcn_mfma_f32_16x16x32_bf16(pa, vf, acc[dyb], 0, 0, 0);
      }
      den = __builtin_amdgcn_mfma_f32_16x16x32_bf16(pa, vones, den, 0, 0, 0);
    }

    __syncthreads();   // all waves done reading before next stage overwrites
  }

  // --- accumulate eighth partials; D: t_rel = 4g+r, dy = dyb*16+lr (R24 body) ---
  #pragma unroll
  for (int dyb = 0; dyb < 2; ++dyb)
    #pragma unroll
    for (int r = 0; r < 4; ++r)
      atomicAdd(&outAcc[(tbase + 4 * g + r) * 32 + dyb * 16 + lr], acc[dyb][r]);
  if (lr == 0) {
    #pragma unroll
    for (int r = 0; r < 4; ++r)
      atomicAdd(&denA[tbase + 4 * g + r], den[r]);
  }
}

// out[t][dy] = num_sum / den_sum
__global__ void divide_kernel(float* __restrict__ out, const float* __restrict__ denA)
{
  int i = blockIdx.x * 256 + threadIdx.x;   // 8192*32
  out[i] = out[i] / denA[i >> 5];
}

extern "C" void kernel_launch(void* const* d_in, const int* in_sizes, int n_in,
                              void* d_out, int out_size, void* d_ws, size_t ws_size,
                              hipStream_t stream)
{
  const float* zc = (const float*)d_in[0];   // z_context (8192,64)
  const float* yc = (const float*)d_in[1];   // y_context (8192,32)
  const float* zt = (const float*)d_in[2];   // z_target  (8192,64)
  const float* W  = (const float*)d_in[3];   // W (64,64)

  unsigned short* Qh = (unsigned short*)d_ws;        // 8192*64 u16
  unsigned short* Ql = Qh + 8192 * 64;
  unsigned short* Kh = Ql + 8192 * 64;
  unsigned short* Kl = Kh + 8192 * 64;
  unsigned short* Vt = Kl + 8192 * 64;               // 32*8192 u16
  float* bias = (float*)(Vt + 32 * 8192);            // 8192 f32
  float* Msym = bias + 8192;                         // 4096 f32
  float* denA = Msym + 4096;                         // 8192 f32 (ws total ~4.83 MB)
  float* out  = (float*)d_out;

  msym_kernel<<<1072, 256, 0, stream>>>(W, Msym, out, denA);
  prep_kernel<<<3104, 256, 0, stream>>>(zc, yc, zt, Msym, Qh, Ql, Kh, Kl, Vt, bias);
  attn_kernel<<<512, 512, 0, stream>>>(Qh, Ql, Kh, Kl, Vt, bias, out, denA);
  divide_kernel<<<1024, 256, 0, stream>>>(out, denA);
}

// Round 26
// 61.395 us; speedup vs baseline: 1.0683x; 1.0683x over previous
//
#include <hip/hip_runtime.h>
#include <hip/hip_bf16.h>

// Interpolator == attention: out = softmax_c(z_t^T (W+W^T) z_c - q_cc[c]) @ y_context
// Msym = log2e*(W+W^T) f32; Q = z_target @ Msym (hi/lo bf16); K = z_context
// (PLAIN bf16 -- lo half dropped, see below); bias[c] = -0.5 z_c^T Msym z_c;
// V^T bf16 [32][8192]. No online max.
//
// R26 = R24 (best attn: 41.9us) + K single-bf16. Dropping Kl loses the
// kl*qh logit term: sigma ~ sqrt(64)*0.67*(0.002*0.58) ~ 0.006 log2-units
// -> ~0.4% weight error, <=0.01 output error (threshold 0.0756, current
// 0.0156). Pure DELETION within the proven structure: KlL array, its stage
// line, 2 MFMAs/cb, prep Kl store. DS/wave-st 576 -> 384 cyc (the binding
// resource per R25's occupancy-null result). Tile back to 128 ctx (R25's 64
// regressed via barrier overhead). LDS 59392 B, 2 blocks/CU.

typedef float f32x4 __attribute__((ext_vector_type(4)));
typedef __bf16 bf16x8 __attribute__((ext_vector_type(8)));

#define LOG2E 1.4426950408889634f

static __device__ __forceinline__ unsigned short f2bf(float x) {
  unsigned u = __float_as_uint(x);
  u += 0x7fffu + ((u >> 16) & 1u);   // RNE
  return (unsigned short)(u >> 16);
}
static __device__ __forceinline__ float bf2f(unsigned short h) {
  return __uint_as_float(((unsigned)h) << 16);
}
static __device__ __forceinline__ bf16x8 ldg8(const unsigned short* p) {
  uint4 u = *reinterpret_cast<const uint4*>(p);
  return __builtin_bit_cast(bf16x8, u);
}
static __device__ __forceinline__ unsigned cvt_pk_bf16(float lo, float hi) {
  unsigned r;
  asm("v_cvt_pk_bf16_f32 %0, %1, %2" : "=v"(r) : "v"(lo), "v"(hi));
  return r;
}
// direct global->LDS DMA, 16B/lane; LDS dest = wave-uniform base + lane*16
static __device__ __forceinline__ void gl2lds(const unsigned short* g, unsigned short* l) {
  __builtin_amdgcn_global_load_lds(
      (const __attribute__((address_space(1))) unsigned int*)g,
      (__attribute__((address_space(3))) unsigned int*)l, 16, 0, 0);
}

// grid 1072: b<16 -> Msym (4096 elems); b>=16 -> zero out (262144) + denA (8192).
// Coverage: 1056 blocks x 256 = 270336 = 262144 + 8192, EXACT. (R19 byte-exact)
__global__ void msym_kernel(const float* __restrict__ W, float* __restrict__ Msym,
                            float* __restrict__ out, float* __restrict__ denA) {
  int b = blockIdx.x, tid = threadIdx.x;
  if (b < 16) {
    int idx = b * 256 + tid;
    int k = idx >> 6, d = idx & 63;
    Msym[idx] = LOG2E * (W[k * 64 + d] + W[d * 64 + k]);
  } else {
    int idx = (b - 16) * 256 + tid;           // [0, 270336)
    if (idx < 262144) out[idx] = 0.f;
    else denA[idx - 262144] = 0.f;
  }
}

// grid 3104: [0,512) Q (16 t/block) | [512,2560) K | [2560,3072) bias (16 c/block)
//          | [3072,3104) V-transpose   (R24 body; K branch stores Kh only)
__global__ void prep_kernel(const float* __restrict__ zc, const float* __restrict__ yc,
                            const float* __restrict__ zt, const float* __restrict__ Msym,
                            unsigned short* __restrict__ Qh, unsigned short* __restrict__ Ql,
                            unsigned short* __restrict__ Kh,
                            unsigned short* __restrict__ Vt, float* __restrict__ bias)
{
  int b = blockIdx.x, tid = threadIdx.x;
  if (b < 512) {                        // Q = z_t @ Msym, 16 targets/block (4/wave)
    int d = tid & 63, grp = tid >> 6;
    int t0 = b * 16 + grp * 4;          // this wave's 4 targets
    const float* z0 = zt + t0 * 64;
    float q0 = 0.f, q1 = 0.f, q2 = 0.f, q3 = 0.f;
    #pragma unroll 8
    for (int k = 0; k < 64; ++k) {
      float m = Msym[k * 64 + d];       // one coalesced load, reused x4
      q0 = fmaf(z0[k], m, q0);
      q1 = fmaf(z0[64 + k], m, q1);
      q2 = fmaf(z0[128 + k], m, q2);
      q3 = fmaf(z0[192 + k], m, q3);
    }
    float qv[4] = {q0, q1, q2, q3};
    #pragma unroll
    for (int i = 0; i < 4; ++i) {
      int idx = (t0 + i) * 64 + d;
      unsigned short h = f2bf(qv[i]);
      Qh[idx] = h;
      Ql[idx] = f2bf(qv[i] - bf2f(h));
    }
  } else if (b < 2560) {                // K plain bf16
    int idx = (b - 512) * 256 + tid;
    Kh[idx] = f2bf(zc[idx]);
  } else if (b < 3072) {                // bias, 16 contexts/block (4/wave)
    int j = tid & 63, grp = tid >> 6;
    int c0 = (b - 2560) * 16 + grp * 4;
    const float* z0 = zc + c0 * 64;
    float s0 = 0.f, s1 = 0.f, s2 = 0.f, s3 = 0.f;
    #pragma unroll 8
    for (int i = 0; i < 64; ++i) {
      float m = Msym[i * 64 + j];       // one coalesced load, reused x4
      s0 = fmaf(z0[i], m, s0);
      s1 = fmaf(z0[64 + i], m, s1);
      s2 = fmaf(z0[128 + i], m, s2);
      s3 = fmaf(z0[192 + i], m, s3);
    }
    float part[4];
    part[0] = s0 * z0[j];
    part[1] = s1 * z0[64 + j];
    part[2] = s2 * z0[128 + j];
    part[3] = s3 * z0[192 + j];
    #pragma unroll
    for (int i = 0; i < 4; ++i) {
      #pragma unroll
      for (int off = 32; off >= 1; off >>= 1) part[i] += __shfl_xor(part[i], off, 64);
    }
    if (j < 4) bias[c0 + j] = -0.5f * part[j];
  } else {                              // V transpose via LDS (alignment-safe)
    __shared__ float vt[256][33];
    int cbase = (b - 3072) * 256;       // 256 contexts per block
    #pragma unroll
    for (int k = 0; k < 32; ++k) {
      int e = k * 256 + tid;            // e = c_rel*32 + dy, coalesced read
      vt[e >> 5][e & 31] = yc[cbase * 32 + e];
    }
    __syncthreads();
    #pragma unroll
    for (int k = 0; k < 32; ++k)        // k = dy; consecutive tid -> consecutive c
      Vt[k * 8192 + cbase + tid] = f2bf(vt[tid][k]);
  }
}

// ---------------- attention kernel (R24 body, Kl deleted) ----------------
// LDS supertile: 128 contexts, SINGLE-buffered. KhL rows = 128B (64 bf16),
// 8 chunks of 16B, physical chunk p holds logical p ^ (row&7). VL rows = 256B
// (128 bf16), 16 chunks, physical p holds logical p ^ (row&15). Staging
// pre-swizzles the GLOBAL source so the gl2lds LDS dest stays linear (m173).

#define STAGE(C0) { \
  const int C0_ = (C0); \
  _Pragma("unroll") \
  for (int i2 = 0; i2 < 2; ++i2) { \
    int i = wid + i2 * 8;                       /* 16 K instr-groups */ \
    int row = i * 8 + (lane >> 3); \
    int lchunk = (lane & 7) ^ (lane >> 3); \
    gl2lds(Kh + (C0_ + row) * 64 + lchunk * 8, &KhL[i * 512]); \
  } \
  { \
    int row = wid * 4 + (lane >> 4);            /* V rows = dy 0..31 */ \
    int lchunk = (lane & 15) ^ (row & 15); \
    gl2lds(Vt + row * 8192 + C0_ + lchunk * 8, &VL[wid * 512]); \
  } }

__global__ __launch_bounds__(512, 2) void attn_kernel(
    const unsigned short* __restrict__ Qh, const unsigned short* __restrict__ Ql,
    const unsigned short* __restrict__ Kh,
    const unsigned short* __restrict__ Vt, const float* __restrict__ bias,
    float* __restrict__ outAcc, float* __restrict__ denA)
{
  __shared__ unsigned short KhL[128 * 64];      // 16 KB
  __shared__ unsigned short VL[32 * 128];       // 8 KB
  __shared__ __align__(16) uint2 p_lds[8][16][34];  // 34 KB; total 59392 B

  const int tid = threadIdx.x;
  const int wid = tid >> 6, lane = tid & 63;
  const int lr = lane & 15, g = lane >> 4;
  const int tt = blockIdx.x >> 3, cq = blockIdx.x & 7;
  const int tbase = tt * 128 + wid * 16;        // this wave's 16 targets
  const int cqbase = cq * 1024;                 // this block's context eighth

  // Q fragments (B-operand): lane holds Q[tbase + lr][f*32 + 8g .. +7]
  bf16x8 qh[2], ql[2];
  #pragma unroll
  for (int f = 0; f < 2; ++f) {
    int off = (tbase + lr) * 64 + f * 32 + 8 * g;
    qh[f] = ldg8(Qh + off);
    ql[f] = ldg8(Ql + off);
  }

  uint4 ones_bits = make_uint4(0x3F803F80u, 0x3F803F80u, 0x3F803F80u, 0x3F803F80u);
  bf16x8 vones = __builtin_bit_cast(bf16x8, ones_bits);

  f32x4 acc[2];                                 // [dyb]; D: t_rel=4g+r, dy=dyb*16+lr
  f32x4 den;                                    // denominator (all dy cols equal)
  acc[0] = (f32x4)(0.0f);
  acc[1] = (f32x4)(0.0f);
  den = (f32x4)(0.0f);

  for (int st = 0; st < 8; ++st) {
    STAGE(cqbase + st * 128)
    __syncthreads();                            // stage complete (vmcnt drained)

    const int cbias = cqbase + st * 128;

    // --- per-cb fused: QK^T -> +bias -> exp2 -> pack -> p_lds write ---
    #pragma unroll
    for (int cb = 0; cb < 8; ++cb) {
      int row = cb * 16 + lr;
      int phys0 = g ^ (row & 7);
      int phys1 = (4 + g) ^ (row & 7);
      int off0 = row * 64 + phys0 * 8;
      int off1 = row * 64 + phys1 * 8;
      bf16x8 kh0 = __builtin_bit_cast(bf16x8, *reinterpret_cast<const uint4*>(&KhL[off0]));
      bf16x8 kh1 = __builtin_bit_cast(bf16x8, *reinterpret_cast<const uint4*>(&KhL[off1]));
      f32x4 sv = (f32x4)(0.0f);
      sv = __builtin_amdgcn_mfma_f32_16x16x32_bf16(kh0, qh[0], sv, 0, 0, 0);
      sv = __builtin_amdgcn_mfma_f32_16x16x32_bf16(kh0, ql[0], sv, 0, 0, 0);
      sv = __builtin_amdgcn_mfma_f32_16x16x32_bf16(kh1, qh[1], sv, 0, 0, 0);
      sv = __builtin_amdgcn_mfma_f32_16x16x32_bf16(kh1, ql[1], sv, 0, 0, 0);
      // D-layout: element r <-> context cb*16 + 4g + r, target = tbase + lr
      f32x4 bv = *reinterpret_cast<const f32x4*>(bias + cbias + cb * 16 + 4 * g);
      float p0 = __builtin_amdgcn_exp2f(sv[0] + bv[0]);
      float p1 = __builtin_amdgcn_exp2f(sv[1] + bv[1]);
      float p2 = __builtin_amdgcn_exp2f(sv[2] + bv[2]);
      float p3 = __builtin_amdgcn_exp2f(sv[3] + bv[3]);
      uint2 w2;
      w2.x = cvt_pk_bf16(p0, p1);
      w2.y = cvt_pk_bf16(p2, p3);
      p_lds[wid][lr][cb * 4 + g] = w2;          // entry e holds contexts 4e..4e+3
    }

    // --- PV + ones-denominator over 4 k-slices of 32 contexts (R24 body) ---
    #pragma unroll
    for (int ks = 0; ks < 4; ++ks) {
      uint2 ra = p_lds[wid][lr][ks * 8 + 2 * g];        // c = ks*32+8g .. +3
      uint2 rb = p_lds[wid][lr][ks * 8 + 2 * g + 1];    // c = ks*32+8g+4 .. +7
      bf16x8 pa = __builtin_bit_cast(bf16x8, make_uint4(ra.x, ra.y, rb.x, rb.y));
      #pragma unroll
      for (int dyb = 0; dyb < 2; ++dyb) {
        int row = dyb * 16 + lr;
        int phys = (ks * 4 + g) ^ lr;           // row & 15 == lr
        bf16x8 vf = __builtin_bit_cast(bf16x8, *reinterpret_cast<const uint4*>(&VL[row * 128 + phys * 8]));
        acc[dyb] = __builtin_amdgcn_mfma_f32_16x16x32_bf16(pa, vf, acc[dyb], 0, 0, 0);
      }
      den = __builtin_amdgcn_mfma_f32_16x16x32_bf16(pa, vones, den, 0, 0, 0);
    }

    __syncthreads();   // all waves done reading before next stage overwrites
  }

  // --- accumulate eighth partials; D: t_rel = 4g+r, dy = dyb*16+lr (R24 body) ---
  #pragma unroll
  for (int dyb = 0; dyb < 2; ++dyb)
    #pragma unroll
    for (int r = 0; r < 4; ++r)
      atomicAdd(&outAcc[(tbase + 4 * g + r) * 32 + dyb * 16 + lr], acc[dyb][r]);
  if (lr == 0) {
    #pragma unroll
    for (int r = 0; r < 4; ++r)
      atomicAdd(&denA[tbase + 4 * g + r], den[r]);
  }
}

// out[t][dy] = num_sum / den_sum
__global__ void divide_kernel(float* __restrict__ out, const float* __restrict__ denA)
{
  int i = blockIdx.x * 256 + threadIdx.x;   // 8192*32
  out[i] = out[i] / denA[i >> 5];
}

extern "C" void kernel_launch(void* const* d_in, const int* in_sizes, int n_in,
                              void* d_out, int out_size, void* d_ws, size_t ws_size,
                              hipStream_t stream)
{
  const float* zc = (const float*)d_in[0];   // z_context (8192,64)
  const float* yc = (const float*)d_in[1];   // y_context (8192,32)
  const float* zt = (const float*)d_in[2];   // z_target  (8192,64)
  const float* W  = (const float*)d_in[3];   // W (64,64)

  unsigned short* Qh = (unsigned short*)d_ws;        // 8192*64 u16
  unsigned short* Ql = Qh + 8192 * 64;
  unsigned short* Kh = Ql + 8192 * 64;
  unsigned short* KlSlot = Kh + 8192 * 64;           // UNUSED (keeps ws layout)
  unsigned short* Vt = KlSlot + 8192 * 64;           // 32*8192 u16
  float* bias = (float*)(Vt + 32 * 8192);            // 8192 f32
  float* Msym = bias + 8192;                         // 4096 f32
  float* denA = Msym + 4096;                         // 8192 f32 (ws total ~4.83 MB)
  float* out  = (float*)d_out;

  msym_kernel<<<1072, 256, 0, stream>>>(W, Msym, out, denA);
  prep_kernel<<<3104, 256, 0, stream>>>(zc, yc, zt, Msym, Qh, Ql, Kh, Vt, bias);
  attn_kernel<<<512, 512, 0, stream>>>(Qh, Ql, Kh, Vt, bias, out, denA);
  divide_kernel<<<1024, 256, 0, stream>>>(out, denA);
}